// Round 1
// baseline (493.213 us; speedup 1.0000x reference)
//
#include <hip/hip_runtime.h>
#include <hip/hip_bf16.h>

typedef __bf16 bf16_t;
typedef __bf16 bf16x8 __attribute__((ext_vector_type(8)));
typedef float f32x4 __attribute__((ext_vector_type(4)));

#define DEVI static __device__ __forceinline__

static constexpr int E_ = 8, C_ = 1024, DIN = 4096, DOUT = 1024, TOK = 4096;
static constexpr int BM = 128, BN = 64, BK = 64;

// ---- workspace layout (bytes) ----
static constexpr size_t WS_WT  = 0;                                      // [E][DOUT][DIN] bf16
static constexpr size_t WS_RWT = WS_WT  + (size_t)E_ * DOUT * DIN * 2;   // [DOUT][DIN] bf16
static constexpr size_t WS_EOT = WS_RWT + (size_t)DOUT * DIN * 2;        // [DOUT][E*C] bf16
static constexpr size_t WS_CMB = WS_EOT + (size_t)DOUT * E_ * C_ * 2;    // [TOK][DOUT] f32

// ============ prepass: transpose + cast weights to bf16 [out][in] ============
__global__ __launch_bounds__(256)
void transpose_cast_kernel(const float* __restrict__ expert_w,
                           const float* __restrict__ residual_w,
                           bf16_t* __restrict__ wt, bf16_t* __restrict__ rwt)
{
    __shared__ float tile[32][33];
    const int z = blockIdx.z;
    const float* src;
    bf16_t* dst;
    if (z < 8) { src = expert_w + (size_t)z * DIN * DOUT; dst = wt + (size_t)z * DOUT * DIN; }
    else       { src = residual_w;                         dst = rwt; }
    const int c0 = blockIdx.x * 32;   // col in src  (DOUT dim)
    const int r0 = blockIdx.y * 32;   // row in src  (DIN dim)
    const int tx = threadIdx.x, ty = threadIdx.y;  // 32 x 8
#pragma unroll
    for (int k = 0; k < 4; ++k)
        tile[ty + 8 * k][tx] = src[(size_t)(r0 + ty + 8 * k) * DOUT + c0 + tx];
    __syncthreads();
#pragma unroll
    for (int k = 0; k < 4; ++k)
        dst[(size_t)(c0 + ty + 8 * k) * DIN + r0 + tx] = (bf16_t)tile[tx][ty + 8 * k];
}

// ============ LDS staging helpers (tile is [ROWS][64] bf16, K-contig) ============
template<int NELEM>  // NELEM = ROWS*64
DEVI void stage_bf16(bf16_t* lds, const bf16_t* g, int ld, int tid)
{
    constexpr int PER_WAVE = NELEM / 4;      // elems per wave
    constexpr int NI = PER_WAVE / 512;       // 512 elems (1 KiB) per global_load_lds wave-instr
    const int w = tid >> 6, l = tid & 63;
#pragma unroll
    for (int i = 0; i < NI; ++i) {
        const int eoff = w * PER_WAVE + i * 512 + l * 8;
        const int r = eoff >> 6, c = eoff & 63;
        const bf16_t* gp = g + (size_t)r * ld + c;
        bf16_t* lp = lds + w * PER_WAVE + i * 512;   // wave-uniform base; HW adds lane*16B
        __builtin_amdgcn_global_load_lds(
            (const __attribute__((address_space(1))) void*)gp,
            (__attribute__((address_space(3))) void*)lp, 16, 0, 0);
    }
}

template<int NELEM>
DEVI void stage_f32(bf16_t* lds, const float* g, int ld, int tid)
{
    constexpr int NI = NELEM / 2048;         // 256 threads * 8 elems
#pragma unroll
    for (int i = 0; i < NI; ++i) {
        const int eoff = i * 2048 + tid * 8;
        const int r = eoff >> 6, c = eoff & 63;
        const float* gp = g + (size_t)r * ld + c;
        f32x4 v0 = *(const f32x4*)(gp);
        f32x4 v1 = *(const f32x4*)(gp + 4);
        bf16x8 h;
        h[0] = (bf16_t)v0[0]; h[1] = (bf16_t)v0[1];
        h[2] = (bf16_t)v0[2]; h[3] = (bf16_t)v0[3];
        h[4] = (bf16_t)v1[0]; h[5] = (bf16_t)v1[1];
        h[6] = (bf16_t)v1[2]; h[7] = (bf16_t)v1[3];
        *(bf16x8*)(lds + eoff) = h;
    }
}

// ============ GEMM: C[M][N] = A[M][K] * B[N][K]^T  (both operands K-contig) ============
// MODE 0: A = WT_e (bf16 ws), B = front_e (f32), out = EOT bf16 (+expert_b by row)
// MODE 1: A = combine_weights (f32), B = EOT (bf16 ws), out = combined f32
// MODE 2: A = inputs tail (f32), B = RWT (bf16 ws), out = d_out f32 blended
template<int MODE>
__global__ __launch_bounds__(256)
void moe_gemm(const void* __restrict__ Ap, const void* __restrict__ Bp,
              void* __restrict__ Op, const float* __restrict__ bias,
              const float* __restrict__ cmb, const float* __restrict__ rw,
              int K, int ldA, int ldB)
{
    __shared__ bf16_t As[BM * BK];
    __shared__ bf16_t Bs[BN * BK];
    const int tid = threadIdx.x;
    const int brow = blockIdx.y * BM, bcol = blockIdx.x * BN;
    const int e = blockIdx.z;

    const bf16_t* Abf = nullptr; const float* Af = nullptr;
    const bf16_t* Bbf = nullptr; const float* Bf = nullptr;
    const float* biasp = bias;
    if constexpr (MODE == 0) {
        Abf = (const bf16_t*)Ap + (size_t)e * DOUT * DIN + (size_t)brow * ldA;
        Bf  = (const float*)Bp + (size_t)e * C_ * DIN + (size_t)bcol * ldB;
        biasp = bias + e * DOUT;
    } else {
        Af  = (const float*)Ap + (size_t)brow * ldA;
        Bbf = (const bf16_t*)Bp + (size_t)bcol * ldB;
    }

    const int w = tid >> 6, l = tid & 63;
    const int wr = (w >> 1) * 64, wc = (w & 1) * 32;   // wave tile 64x32
    const int lr = l & 15, lk = l >> 4;

    f32x4 acc[4][2] = {};

    for (int k0 = 0; k0 < K; k0 += BK) {
        if constexpr (MODE == 0) {
            stage_bf16<BM * BK>(As, Abf + k0, ldA, tid);
            stage_f32<BN * BK>(Bs, Bf + k0, ldB, tid);
        } else {
            stage_f32<BM * BK>(As, Af + k0, ldA, tid);
            stage_bf16<BN * BK>(Bs, Bbf + k0, ldB, tid);
        }
        __syncthreads();
#pragma unroll
        for (int kk = 0; kk < 2; ++kk) {
            bf16x8 a[4], b[2];
#pragma unroll
            for (int m = 0; m < 4; ++m)
                a[m] = *(const bf16x8*)(&As[(wr + m * 16 + lr) * BK + kk * 32 + lk * 8]);
#pragma unroll
            for (int n = 0; n < 2; ++n)
                b[n] = *(const bf16x8*)(&Bs[(wc + n * 16 + lr) * BK + kk * 32 + lk * 8]);
#pragma unroll
            for (int m = 0; m < 4; ++m)
#pragma unroll
                for (int n = 0; n < 2; ++n)
                    acc[m][n] = __builtin_amdgcn_mfma_f32_16x16x32_bf16(a[m], b[n], acc[m][n], 0, 0, 0);
        }
        __syncthreads();
    }

    // epilogue: C/D frag layout col=lane&15, row=(lane>>4)*4+j  [m89/m91 verified]
#pragma unroll
    for (int m = 0; m < 4; ++m) {
#pragma unroll
        for (int n = 0; n < 2; ++n) {
            const int colL = wc + n * 16 + lr;
#pragma unroll
            for (int j = 0; j < 4; ++j) {
                const int rowL = wr + m * 16 + lk * 4 + j;
                const int r = brow + rowL, c = bcol + colL;
                const float v = acc[m][n][j];
                if constexpr (MODE == 0) {
                    ((bf16_t*)Op)[(size_t)r * (E_ * C_) + e * C_ + c] = (bf16_t)(v + biasp[r]);
                } else if constexpr (MODE == 1) {
                    ((float*)Op)[(size_t)r * DOUT + c] = v;
                } else {
                    const float w0 = rw[2 * r], w1 = rw[2 * r + 1];
                    ((float*)Op)[(size_t)r * DOUT + c] =
                        cmb[(size_t)r * DOUT + c] * w0 + (v + biasp[c]) * w1;
                }
            }
        }
    }
}

extern "C" void kernel_launch(void* const* d_in, const int* in_sizes, int n_in,
                              void* d_out, int out_size, void* d_ws, size_t ws_size,
                              hipStream_t stream)
{
    const float* inputs     = (const float*)d_in[0];
    const float* expert_w   = (const float*)d_in[1];
    const float* expert_b   = (const float*)d_in[2];
    const float* residual_w = (const float*)d_in[3];
    const float* residual_b = (const float*)d_in[4];
    const float* combine_w  = (const float*)d_in[5];
    const float* resid_wt   = (const float*)d_in[6];
    float* out = (float*)d_out;
    char* ws = (char*)d_ws;

    bf16_t* WT  = (bf16_t*)(ws + WS_WT);
    bf16_t* RWT = (bf16_t*)(ws + WS_RWT);
    bf16_t* EOT = (bf16_t*)(ws + WS_EOT);
    float*  CMB = (float*)(ws + WS_CMB);

    // 1) weights -> bf16 transposed
    transpose_cast_kernel<<<dim3(32, 128, 9), dim3(32, 8), 0, stream>>>(
        expert_w, residual_w, WT, RWT);

    // 2) expert GEMM: EOT[m][e*C+c] = sum_d WT_e[m][d]*front_e[c][d] + expert_b[e][m]
    moe_gemm<0><<<dim3(C_ / BN, DOUT / BM, E_), 256, 0, stream>>>(
        WT, inputs, EOT, expert_b, nullptr, nullptr, DIN, DIN, DIN);

    // 3) combine GEMM: CMB[s][m] = sum_ec cw[s][ec]*EOT[m][ec]
    moe_gemm<1><<<dim3(DOUT / BN, TOK / BM, 1), 256, 0, stream>>>(
        combine_w, EOT, CMB, nullptr, nullptr, nullptr, E_ * C_, E_ * C_, E_ * C_);

    // 4) residual GEMM + blend: out[s][m] = CMB[s][m]*w0 + (resid+residual_b)*w1
    moe_gemm<2><<<dim3(DOUT / BN, TOK / BM, 1), 256, 0, stream>>>(
        inputs + (size_t)E_ * C_ * DIN, RWT, out, residual_b, CMB, resid_wt,
        DIN, DIN, DIN);
}

// Round 2
// 416.004 us; speedup vs baseline: 1.1856x; 1.1856x over previous
//
#include <hip/hip_runtime.h>
#include <hip/hip_bf16.h>

typedef __bf16 bf16_t;
typedef __bf16 bf16x8 __attribute__((ext_vector_type(8)));
typedef float f32x4 __attribute__((ext_vector_type(4)));

#define DEVI static __device__ __forceinline__

static constexpr int E_ = 8, C_ = 1024, DIN = 4096, DOUT = 1024, TOK = 4096;
static constexpr int BM = 128, BN = 128, BK = 64;
static constexpr int NT = 512;                 // 8 waves / block

// ---- workspace layout (bytes) ----
static constexpr size_t WS_WT  = 0;                                      // [E][DOUT][DIN] bf16 (swizzled)
static constexpr size_t WS_RWT = WS_WT  + (size_t)E_ * DOUT * DIN * 2;   // [DOUT][DIN] bf16 (swizzled)
static constexpr size_t WS_EOT = WS_RWT + (size_t)DOUT * DIN * 2;        // [DOUT][E*C] bf16 (swizzled)

// XOR-swizzle within each 64-element K-group: chunk(col>>3 & 7) ^= row&7.
// Applied to the GLOBAL layout of all bf16 ws operands (global_load_lds copies
// linearly, rule 21: pre-swizzle source + swizzle the LDS read).
DEVI int swz(int row, int col) {
    return (col & ~63) | ((col & 56) ^ ((row & 7) << 3)) | (col & 7);
}

// ============ prepass: transpose + cast weights to bf16 [out][in], swizzled ============
__global__ __launch_bounds__(256)
void transpose_cast_kernel(const float* __restrict__ expert_w,
                           const float* __restrict__ residual_w,
                           bf16_t* __restrict__ wt, bf16_t* __restrict__ rwt)
{
    __shared__ float tile[32][33];
    const int z = blockIdx.z;
    const float* src;
    bf16_t* dst;
    if (z < 8) { src = expert_w + (size_t)z * DIN * DOUT; dst = wt + (size_t)z * DOUT * DIN; }
    else       { src = residual_w;                         dst = rwt; }
    const int c0 = blockIdx.x * 32;   // col in src  (DOUT dim -> dst row)
    const int r0 = blockIdx.y * 32;   // row in src  (DIN dim  -> dst col/K)
    const int tx = threadIdx.x, ty = threadIdx.y;  // 32 x 8
#pragma unroll
    for (int k = 0; k < 4; ++k)
        tile[ty + 8 * k][tx] = src[(size_t)(r0 + ty + 8 * k) * DOUT + c0 + tx];
    __syncthreads();
#pragma unroll
    for (int k = 0; k < 4; ++k) {
        const int row = c0 + ty + 8 * k;      // DOUT
        const int col = r0 + tx;              // DIN (K)
        dst[(size_t)row * DIN + swz(row, col)] = (bf16_t)tile[tx][ty + 8 * k];
    }
}

// ============ LDS staging ============
// bf16 ws operand: linear DMA copy (source is pre-swizzled in ws)
template<int NELEM>
DEVI void stage_bf16(bf16_t* lds, const bf16_t* g, int ld, int tid)
{
    constexpr int PER_WAVE = NELEM / 8;
    constexpr int NI = PER_WAVE / 512;
    const int w = tid >> 6, l = tid & 63;
#pragma unroll
    for (int i = 0; i < NI; ++i) {
        const int eoff = w * PER_WAVE + i * 512 + l * 8;
        const int r = eoff >> 6, c = eoff & 63;
        const bf16_t* gp = g + (size_t)r * ld + c;
        bf16_t* lp = lds + w * PER_WAVE + i * 512;   // wave-uniform base; HW adds lane*16B
        __builtin_amdgcn_global_load_lds(
            (const __attribute__((address_space(1))) void*)gp,
            (__attribute__((address_space(3))) void*)lp, 16, 0, 0);
    }
}

// f32 operand: reg-stage + cvt + swizzled ds_write
template<int NELEM>
DEVI void stage_f32(bf16_t* lds, const float* g, int ld, int tid)
{
    constexpr int NI = NELEM / (NT * 8);
#pragma unroll
    for (int i = 0; i < NI; ++i) {
        const int eoff = i * NT * 8 + tid * 8;
        const int r = eoff >> 6, c = eoff & 63;        // c is 8-aligned
        const float* gp = g + (size_t)r * ld + c;
        f32x4 v0 = *(const f32x4*)(gp);
        f32x4 v1 = *(const f32x4*)(gp + 4);
        bf16x8 h;
        h[0] = (bf16_t)v0[0]; h[1] = (bf16_t)v0[1];
        h[2] = (bf16_t)v0[2]; h[3] = (bf16_t)v0[3];
        h[4] = (bf16_t)v1[0]; h[5] = (bf16_t)v1[1];
        h[6] = (bf16_t)v1[2]; h[7] = (bf16_t)v1[3];
        const int cs = (c & 56) ^ ((r & 7) << 3);
        *(bf16x8*)(lds + r * 64 + cs) = h;
    }
}

// ============ expert GEMM: EOT[m][e*C+c] = sum_d WT_e[m][d]*front_e[c][d] + b ============
__global__ __launch_bounds__(NT, 4)
void expert_gemm(const bf16_t* __restrict__ WT, const float* __restrict__ inputs,
                 bf16_t* __restrict__ EOT, const float* __restrict__ expert_b)
{
    __shared__ bf16_t As[BM * BK];
    __shared__ bf16_t Bs[BN * BK];
    const int tid = threadIdx.x;
    const int e = blockIdx.z;
    const int brow = blockIdx.y * BM;   // DOUT
    const int bcol = blockIdx.x * BN;   // C
    const bf16_t* A = WT + (size_t)e * DOUT * DIN + (size_t)brow * DIN;
    const float*  B = inputs + (size_t)e * C_ * DIN + (size_t)bcol * DIN;

    const int w = tid >> 6, l = tid & 63;
    const int wr = (w >> 1) * 32, wc = (w & 1) * 64;   // wave tile 32x64
    const int lr = l & 15, lk = l >> 4, sw = (l & 7) << 3;

    f32x4 acc[2][4] = {};

    for (int k0 = 0; k0 < DIN; k0 += BK) {
        stage_bf16<BM * BK>(As, A + k0, DIN, tid);
        stage_f32<BN * BK>(Bs, B + k0, DIN, tid);
        __syncthreads();
#pragma unroll
        for (int kk = 0; kk < 2; ++kk) {
            const int cs = (kk * 32 + lk * 8) ^ sw;
            bf16x8 a[2], b[4];
#pragma unroll
            for (int m = 0; m < 2; ++m)
                a[m] = *(const bf16x8*)(&As[(wr + m * 16 + lr) * BK + cs]);
#pragma unroll
            for (int n = 0; n < 4; ++n)
                b[n] = *(const bf16x8*)(&Bs[(wc + n * 16 + lr) * BK + cs]);
#pragma unroll
            for (int m = 0; m < 2; ++m)
#pragma unroll
                for (int n = 0; n < 4; ++n)
                    acc[m][n] = __builtin_amdgcn_mfma_f32_16x16x32_bf16(a[m], b[n], acc[m][n], 0, 0, 0);
        }
        __syncthreads();
    }

    // C/D frag: col=lane&15, row=(lane>>4)*4+j ; write EOT swizzled (K-dim = ec)
#pragma unroll
    for (int m = 0; m < 2; ++m) {
#pragma unroll
        for (int n = 0; n < 4; ++n) {
            const int col = bcol + wc + n * 16 + lr;     // C index
#pragma unroll
            for (int j = 0; j < 4; ++j) {
                const int row = brow + wr + m * 16 + lk * 4 + j;   // DOUT index
                const int ec = e * C_ + col;
                EOT[(size_t)row * (E_ * C_) + swz(row, ec)] =
                    (bf16_t)(acc[m][n][j] + expert_b[e * DOUT + row]);
            }
        }
    }
}

// ============ fused combine+residual GEMM, z-split K, atomic blend ============
// z=0: out += w0 * sum_{ec<4096}  cw[s][ec]   * EOT[m][ec]
// z=1: out += w0 * sum_{ec>=4096} cw[s][ec]   * EOT[m][ec]
// z=2: out += w1 * (sum_d x[s][d] * RWT[m][d] + residual_b[m])
__global__ __launch_bounds__(NT, 4)
void combine_gemm(const float* __restrict__ cw, const bf16_t* __restrict__ EOT,
                  const float* __restrict__ xtail, const bf16_t* __restrict__ RWT,
                  const float* __restrict__ residual_b, const float* __restrict__ rw,
                  float* __restrict__ out)
{
    __shared__ bf16_t As[BM * BK];   // f32-sourced (cw or x), M = tokens
    __shared__ bf16_t Bs[BN * BK];   // bf16 ws (EOT or RWT), N = DOUT
    const int tid = threadIdx.x;
    const int z = blockIdx.z;
    const int brow = blockIdx.y * BM;   // token
    const int bcol = blockIdx.x * BN;   // DOUT

    const float* A;
    const bf16_t* B;
    int ld;
    if (z == 0)      { A = cw + (size_t)brow * 8192;        B = EOT + (size_t)bcol * 8192;        ld = 8192; }
    else if (z == 1) { A = cw + (size_t)brow * 8192 + 4096; B = EOT + (size_t)bcol * 8192 + 4096; ld = 8192; }
    else             { A = xtail + (size_t)brow * 4096;     B = RWT + (size_t)bcol * 4096;        ld = 4096; }

    const int w = tid >> 6, l = tid & 63;
    const int wr = (w >> 1) * 32, wc = (w & 1) * 64;
    const int lr = l & 15, lk = l >> 4, sw = (l & 7) << 3;

    f32x4 acc[2][4] = {};

    for (int k0 = 0; k0 < 4096; k0 += BK) {
        stage_f32<BM * BK>(As, A + k0, ld, tid);
        stage_bf16<BN * BK>(Bs, B + k0, ld, tid);
        __syncthreads();
#pragma unroll
        for (int kk = 0; kk < 2; ++kk) {
            const int cs = (kk * 32 + lk * 8) ^ sw;
            bf16x8 a[2], b[4];
#pragma unroll
            for (int m = 0; m < 2; ++m)
                a[m] = *(const bf16x8*)(&As[(wr + m * 16 + lr) * BK + cs]);
#pragma unroll
            for (int n = 0; n < 4; ++n)
                b[n] = *(const bf16x8*)(&Bs[(wc + n * 16 + lr) * BK + cs]);
#pragma unroll
            for (int m = 0; m < 2; ++m)
#pragma unroll
                for (int n = 0; n < 4; ++n)
                    acc[m][n] = __builtin_amdgcn_mfma_f32_16x16x32_bf16(a[m], b[n], acc[m][n], 0, 0, 0);
        }
        __syncthreads();
    }

#pragma unroll
    for (int m = 0; m < 2; ++m) {
#pragma unroll
        for (int n = 0; n < 4; ++n) {
            const int col = bcol + wc + n * 16 + lr;     // DOUT
#pragma unroll
            for (int j = 0; j < 4; ++j) {
                const int row = brow + wr + m * 16 + lk * 4 + j;   // token
                float v = acc[m][n][j];
                if (z == 2) v += residual_b[col];
                const float scale = rw[2 * row + (z == 2 ? 1 : 0)];
                atomicAdd(&out[(size_t)row * DOUT + col], scale * v);
            }
        }
    }
}

extern "C" void kernel_launch(void* const* d_in, const int* in_sizes, int n_in,
                              void* d_out, int out_size, void* d_ws, size_t ws_size,
                              hipStream_t stream)
{
    const float* inputs     = (const float*)d_in[0];
    const float* expert_w   = (const float*)d_in[1];
    const float* expert_b   = (const float*)d_in[2];
    const float* residual_w = (const float*)d_in[3];
    const float* residual_b = (const float*)d_in[4];
    const float* combine_w  = (const float*)d_in[5];
    const float* resid_wt   = (const float*)d_in[6];
    float* out = (float*)d_out;
    char* ws = (char*)d_ws;

    bf16_t* WT  = (bf16_t*)(ws + WS_WT);
    bf16_t* RWT = (bf16_t*)(ws + WS_RWT);
    bf16_t* EOT = (bf16_t*)(ws + WS_EOT);

    // 0) zero the output (blend accumulates atomically)
    hipMemsetAsync(d_out, 0, (size_t)out_size * sizeof(float), stream);

    // 1) weights -> bf16 transposed + swizzled
    transpose_cast_kernel<<<dim3(32, 128, 9), dim3(32, 8), 0, stream>>>(
        expert_w, residual_w, WT, RWT);

    // 2) expert GEMM -> EOT (bf16, swizzled, [DOUT][E*C])
    expert_gemm<<<dim3(C_ / BN, DOUT / BM, E_), NT, 0, stream>>>(
        WT, inputs, EOT, expert_b);

    // 3) fused combine (K split in 2) + residual, atomic blend into out
    combine_gemm<<<dim3(DOUT / BN, TOK / BM, 3), NT, 0, stream>>>(
        combine_w, EOT, inputs + (size_t)E_ * C_ * DIN, RWT,
        residual_b, resid_wt, out);
}

// Round 3
// 328.634 us; speedup vs baseline: 1.5008x; 1.2659x over previous
//
#include <hip/hip_runtime.h>
#include <hip/hip_bf16.h>

typedef __bf16 bf16_t;
typedef __bf16 bf16x8 __attribute__((ext_vector_type(8)));
typedef float f32x4 __attribute__((ext_vector_type(4)));

#define DEVI static __device__ __forceinline__

static constexpr int E_ = 8, C_ = 1024, DIN = 4096, DOUT = 1024, TOK = 4096;
static constexpr int BM = 128, BN = 128, BK = 64;
static constexpr int NT = 512;                 // 8 waves / block

// ---- workspace layout (bytes) ----
static constexpr size_t WS_WT  = 0;                                      // [E][DOUT][DIN] bf16 (swizzled)
static constexpr size_t WS_RWT = WS_WT  + (size_t)E_ * DOUT * DIN * 2;   // [DOUT][DIN] bf16 (swizzled)
static constexpr size_t WS_EOT = WS_RWT + (size_t)DOUT * DIN * 2;        // [DOUT][E*C] bf16 (swizzled)

// XOR-swizzle within each 64-element K-group: chunk(col>>3 & 7) ^= row&7.
// Applied to the GLOBAL layout of bf16 ws operands (global_load_lds copies
// linearly, rule 21: pre-swizzle source + swizzle the LDS read).
DEVI int swz(int row, int col) {
    return (col & ~63) | ((col & 56) ^ ((row & 7) << 3)) | (col & 7);
}

// ============ prepass: transpose + cast weights to bf16 [out][in], swizzled ============
__global__ __launch_bounds__(256)
void transpose_cast_kernel(const float* __restrict__ expert_w,
                           const float* __restrict__ residual_w,
                           bf16_t* __restrict__ wt, bf16_t* __restrict__ rwt)
{
    __shared__ float tile[32][33];
    const int z = blockIdx.z;
    const float* src;
    bf16_t* dst;
    if (z < 8) { src = expert_w + (size_t)z * DIN * DOUT; dst = wt + (size_t)z * DOUT * DIN; }
    else       { src = residual_w;                         dst = rwt; }
    const int c0 = blockIdx.x * 32;   // col in src  (DOUT dim -> dst row)
    const int r0 = blockIdx.y * 32;   // row in src  (DIN dim  -> dst col/K)
    const int tx = threadIdx.x, ty = threadIdx.y;  // 32 x 8
#pragma unroll
    for (int k = 0; k < 4; ++k)
        tile[ty + 8 * k][tx] = src[(size_t)(r0 + ty + 8 * k) * DOUT + c0 + tx];
    __syncthreads();
#pragma unroll
    for (int k = 0; k < 4; ++k) {
        const int row = c0 + ty + 8 * k;      // DOUT
        const int col = r0 + tx;              // DIN (K)
        dst[(size_t)row * DIN + swz(row, col)] = (bf16_t)tile[tx][ty + 8 * k];
    }
}

// ============ LDS staging ============
// bf16 ws operand: linear DMA copy (source is pre-swizzled in ws)
template<int NELEM>
DEVI void stage_bf16(bf16_t* lds, const bf16_t* g, int ld, int tid)
{
    constexpr int PER_WAVE = NELEM / 8;
    constexpr int NI = PER_WAVE / 512;
    const int w = tid >> 6, l = tid & 63;
#pragma unroll
    for (int i = 0; i < NI; ++i) {
        const int eoff = w * PER_WAVE + i * 512 + l * 8;
        const int r = eoff >> 6, c = eoff & 63;
        const bf16_t* gp = g + (size_t)r * ld + c;
        bf16_t* lp = lds + w * PER_WAVE + i * 512;   // wave-uniform base; HW adds lane*16B
        __builtin_amdgcn_global_load_lds(
            (const __attribute__((address_space(1))) void*)gp,
            (__attribute__((address_space(3))) void*)lp, 16, 0, 0);
    }
}

// f32 operand: reg-stage + cvt + swizzled ds_write
template<int NELEM>
DEVI void stage_f32(bf16_t* lds, const float* g, int ld, int tid)
{
    constexpr int NI = NELEM / (NT * 8);
#pragma unroll
    for (int i = 0; i < NI; ++i) {
        const int eoff = i * NT * 8 + tid * 8;
        const int r = eoff >> 6, c = eoff & 63;        // c is 8-aligned
        const float* gp = g + (size_t)r * ld + c;
        f32x4 v0 = *(const f32x4*)(gp);
        f32x4 v1 = *(const f32x4*)(gp + 4);
        bf16x8 h;
        h[0] = (bf16_t)v0[0]; h[1] = (bf16_t)v0[1];
        h[2] = (bf16_t)v0[2]; h[3] = (bf16_t)v0[3];
        h[4] = (bf16_t)v1[0]; h[5] = (bf16_t)v1[1];
        h[6] = (bf16_t)v1[2]; h[7] = (bf16_t)v1[3];
        const int cs = (c & 56) ^ ((r & 7) << 3);
        *(bf16x8*)(lds + r * 64 + cs) = h;
    }
}

// ============ expert GEMM: EOT[m][e*C+c] = sum_d WT_e[m][d]*front_e[c][d] + b ============
__global__ __launch_bounds__(NT, 4)
void expert_gemm(const bf16_t* __restrict__ WT, const float* __restrict__ inputs,
                 bf16_t* __restrict__ EOT, const float* __restrict__ expert_b)
{
    __shared__ bf16_t As[BM * BK];
    __shared__ bf16_t Bs[BN * BK];
    const int tid = threadIdx.x;

    // T1: bijective XCD-chunked swizzle. nwg = 512. After remap, chunk k
    // (logical ids [64k, 64k+64)) = exactly expert k -> each XCD streams
    // WT_k + front_k once through its private L2.
    int id = blockIdx.x + 8 * (blockIdx.y + 8 * blockIdx.z);
    id = (id & 7) * 64 + (id >> 3);
    const int bx = id & 7, by = (id >> 3) & 7, e = id >> 6;

    const int brow = by * BM;   // DOUT
    const int bcol = bx * BN;   // C
    const bf16_t* A = WT + (size_t)e * DOUT * DIN + (size_t)brow * DIN;
    const float*  B = inputs + (size_t)e * C_ * DIN + (size_t)bcol * DIN;

    const int w = tid >> 6, l = tid & 63;
    const int wr = (w >> 1) * 32, wc = (w & 1) * 64;   // wave tile 32x64
    const int lr = l & 15, lk = l >> 4, sw = (l & 7) << 3;

    f32x4 acc[2][4] = {};

    for (int k0 = 0; k0 < DIN; k0 += BK) {
        stage_bf16<BM * BK>(As, A + k0, DIN, tid);
        stage_f32<BN * BK>(Bs, B + k0, DIN, tid);
        __syncthreads();
#pragma unroll
        for (int kk = 0; kk < 2; ++kk) {
            const int cs = (kk * 32 + lk * 8) ^ sw;
            bf16x8 a[2], b[4];
#pragma unroll
            for (int m = 0; m < 2; ++m)
                a[m] = *(const bf16x8*)(&As[(wr + m * 16 + lr) * BK + cs]);
#pragma unroll
            for (int n = 0; n < 4; ++n)
                b[n] = *(const bf16x8*)(&Bs[(wc + n * 16 + lr) * BK + cs]);
#pragma unroll
            for (int m = 0; m < 2; ++m)
#pragma unroll
                for (int n = 0; n < 4; ++n)
                    acc[m][n] = __builtin_amdgcn_mfma_f32_16x16x32_bf16(a[m], b[n], acc[m][n], 0, 0, 0);
        }
        __syncthreads();
    }

    // C/D frag: col=lane&15, row=(lane>>4)*4+j ; write EOT swizzled (K-dim = ec)
#pragma unroll
    for (int m = 0; m < 2; ++m) {
#pragma unroll
        for (int n = 0; n < 4; ++n) {
            const int col = bcol + wc + n * 16 + lr;     // C index
#pragma unroll
            for (int j = 0; j < 4; ++j) {
                const int row = brow + wr + m * 16 + lk * 4 + j;   // DOUT index
                const int ec = e * C_ + col;
                EOT[(size_t)row * (E_ * C_) + swz(row, ec)] =
                    (bf16_t)(acc[m][n][j] + expert_b[e * DOUT + row]);
            }
        }
    }
}

// ============ fused combine+residual GEMM, z-split K, atomic blend ============
// z=0: out += w0 * sum_{ec<4096}  cw[s][ec]   * EOT[m][ec]
// z=1: out += w0 * sum_{ec>=4096} cw[s][ec]   * EOT[m][ec]
// z=2: out += w1 * (sum_d x[s][d] * RWT[m][d] + residual_b[m])
__global__ __launch_bounds__(NT, 4)
void combine_gemm(const float* __restrict__ cw, const bf16_t* __restrict__ EOT,
                  const float* __restrict__ xtail, const bf16_t* __restrict__ RWT,
                  const float* __restrict__ residual_b, const float* __restrict__ rw,
                  float* __restrict__ out)
{
    __shared__ bf16_t As[BM * BK];   // f32-sourced (cw or x), M = tokens
    __shared__ bf16_t Bs[BN * BK];   // bf16 ws (EOT or RWT), N = DOUT
    const int tid = threadIdx.x;

    // T1: bijective XCD-chunked swizzle. nwg = 768 -> chunk = 96 logical ids
    // per XCD; the 8 col-tiles sharing one A row-panel are consecutive and
    // co-resident on one XCD's L2.
    int id = blockIdx.x + 8 * (blockIdx.y + 32 * blockIdx.z);
    id = (id & 7) * 96 + (id >> 3);
    const int bx = id & 7, by = (id >> 3) & 31, z = id >> 8;

    const int brow = by * BM;   // token
    const int bcol = bx * BN;   // DOUT

    const float* A;
    const bf16_t* B;
    int ld;
    if (z == 0)      { A = cw + (size_t)brow * 8192;        B = EOT + (size_t)bcol * 8192;        ld = 8192; }
    else if (z == 1) { A = cw + (size_t)brow * 8192 + 4096; B = EOT + (size_t)bcol * 8192 + 4096; ld = 8192; }
    else             { A = xtail + (size_t)brow * 4096;     B = RWT + (size_t)bcol * 4096;        ld = 4096; }

    const int w = tid >> 6, l = tid & 63;
    const int wr = (w >> 1) * 32, wc = (w & 1) * 64;
    const int lr = l & 15, lk = l >> 4, sw = (l & 7) << 3;

    f32x4 acc[2][4] = {};

    for (int k0 = 0; k0 < 4096; k0 += BK) {
        stage_f32<BM * BK>(As, A + k0, ld, tid);
        stage_bf16<BN * BK>(Bs, B + k0, ld, tid);
        __syncthreads();
#pragma unroll
        for (int kk = 0; kk < 2; ++kk) {
            const int cs = (kk * 32 + lk * 8) ^ sw;
            bf16x8 a[2], b[4];
#pragma unroll
            for (int m = 0; m < 2; ++m)
                a[m] = *(const bf16x8*)(&As[(wr + m * 16 + lr) * BK + cs]);
#pragma unroll
            for (int n = 0; n < 4; ++n)
                b[n] = *(const bf16x8*)(&Bs[(wc + n * 16 + lr) * BK + cs]);
#pragma unroll
            for (int m = 0; m < 2; ++m)
#pragma unroll
                for (int n = 0; n < 4; ++n)
                    acc[m][n] = __builtin_amdgcn_mfma_f32_16x16x32_bf16(a[m], b[n], acc[m][n], 0, 0, 0);
        }
        __syncthreads();
    }

#pragma unroll
    for (int m = 0; m < 2; ++m) {
#pragma unroll
        for (int n = 0; n < 4; ++n) {
            const int col = bcol + wc + n * 16 + lr;     // DOUT
#pragma unroll
            for (int j = 0; j < 4; ++j) {
                const int row = brow + wr + m * 16 + lk * 4 + j;   // token
                float v = acc[m][n][j];
                if (z == 2) v += residual_b[col];
                const float scale = rw[2 * row + (z == 2 ? 1 : 0)];
                atomicAdd(&out[(size_t)row * DOUT + col], scale * v);
            }
        }
    }
}

extern "C" void kernel_launch(void* const* d_in, const int* in_sizes, int n_in,
                              void* d_out, int out_size, void* d_ws, size_t ws_size,
                              hipStream_t stream)
{
    const float* inputs     = (const float*)d_in[0];
    const float* expert_w   = (const float*)d_in[1];
    const float* expert_b   = (const float*)d_in[2];
    const float* residual_w = (const float*)d_in[3];
    const float* residual_b = (const float*)d_in[4];
    const float* combine_w  = (const float*)d_in[5];
    const float* resid_wt   = (const float*)d_in[6];
    float* out = (float*)d_out;
    char* ws = (char*)d_ws;

    bf16_t* WT  = (bf16_t*)(ws + WS_WT);
    bf16_t* RWT = (bf16_t*)(ws + WS_RWT);
    bf16_t* EOT = (bf16_t*)(ws + WS_EOT);

    // 0) zero the output (blend accumulates atomically)
    hipMemsetAsync(d_out, 0, (size_t)out_size * sizeof(float), stream);

    // 1) weights -> bf16 transposed + swizzled
    transpose_cast_kernel<<<dim3(32, 128, 9), dim3(32, 8), 0, stream>>>(
        expert_w, residual_w, WT, RWT);

    // 2) expert GEMM -> EOT (bf16, swizzled, [DOUT][E*C])
    expert_gemm<<<dim3(C_ / BN, DOUT / BM, E_), NT, 0, stream>>>(
        WT, inputs, EOT, expert_b);

    // 3) fused combine (K split in 2) + residual, atomic blend into out
    combine_gemm<<<dim3(DOUT / BN, TOK / BM, 3), NT, 0, stream>>>(
        combine_w, EOT, inputs + (size_t)E_ * C_ * DIN, RWT,
        residual_b, resid_wt, out);
}